// Round 1
// baseline (1979.252 us; speedup 1.0000x reference)
//
#include <hip/hip_runtime.h>
#include <cmath>
#include <complex>

#define T_TAB 4096
#define G_TAB 8
#define NN 16384

// ---------------- CG tables (exact host-side port of the reference) ----------------
struct CGPack {
  float c000[1];
  float c110[9];
  float c220[25];
  float c330[49];
  float c011[9];
  float c101[9];
  float c111[27];
  float c121[45];
  float c211[45];
  float c221[75];
  float c231[105];
  float c321[105];
  float c331[147];
};

static double factd(int n){ double r=1.0; for(int i=2;i<=n;++i) r*=(double)i; return r; }

static double cg_coef(int j1,int m1,int j2,int m2,int j3,int m3){
  double pref = sqrt((2.0*j3+1.0)*factd(j3+j1-j2)*factd(j3-j1+j2)*factd(j1+j2-j3)/factd(j1+j2+j3+1));
  pref *= sqrt(factd(j3+m3)*factd(j3-m3)*factd(j1-m1)*factd(j1+m1)*factd(j2-m2)*factd(j2+m2));
  double s=0.0;
  for(int k=0;k<=j1+j2-j3;++k){
    int a0=k,a1=j1+j2-j3-k,a2=j1-m1-k,a3=j2+m2-k,a4=j3-j2+m1+k,a5=j3-j1-m2+k;
    if(a0<0||a1<0||a2<0||a3<0||a4<0||a5<0) continue;
    double d=factd(a0)*factd(a1)*factd(a2)*factd(a3)*factd(a4)*factd(a5);
    s += ((k&1)?-1.0:1.0)/d;
  }
  return pref*s;
}

static void u_fill(int l, std::complex<double> U[7][7]){
  for(int i=0;i<7;++i) for(int j=0;j<7;++j) U[i][j]=std::complex<double>(0.0,0.0);
  const double is2 = 1.0/sqrt(2.0);
  U[l][l]=1.0;
  for(int m=1;m<=l;++m){
    double sgn = (m&1)?-1.0:1.0;
    U[l+m][l+m] = sgn*is2;
    U[l+m][l-m] = is2;
    U[l-m][l-m] = std::complex<double>(0.0, is2);
    U[l-m][l+m] = std::complex<double>(0.0, -sgn*is2);
  }
}

static void cg_fill(int l1,int l2,int l3, float* out){
  int n1=2*l1+1,n2=2*l2+1,n3=2*l3+1;
  double Cc[7][7][7];
  for(int a=0;a<7;++a)for(int b=0;b<7;++b)for(int c=0;c<7;++c) Cc[a][b][c]=0.0;
  for(int m1=-l1;m1<=l1;++m1)
    for(int m2=-l2;m2<=l2;++m2){
      int m3=m1+m2;
      if(m3>=-l3&&m3<=l3) Cc[m1+l1][m2+l2][m3+l3]=cg_coef(l1,m1,l2,m2,l3,m3);
    }
  std::complex<double> U1[7][7],U2[7][7],U3[7][7];
  u_fill(l1,U1); u_fill(l2,U2); u_fill(l3,U3);
  std::complex<double> Cr[343];
  double sre=0.0,sim=0.0;
  for(int a=0;a<n1;++a)for(int b=0;b<n2;++b)for(int c=0;c<n3;++c){
    std::complex<double> acc(0.0,0.0);
    for(int u=0;u<n1;++u)for(int v=0;v<n2;++v)for(int w=0;w<n3;++w){
      double cc=Cc[u][v][w];
      if(cc==0.0) continue;
      acc += U1[a][u]*U2[b][v]*std::conj(U3[c][w])*cc;
    }
    Cr[(a*n2+b)*n3+c]=acc;
    sre+=fabs(acc.real()); sim+=fabs(acc.imag());
  }
  bool useim = sim>sre;
  for(int idx=0;idx<n1*n2*n3;++idx) out[idx]=(float)(useim?Cr[idx].imag():Cr[idx].real());
}

static void build_cg(CGPack& P){
  cg_fill(0,0,0,P.c000);
  cg_fill(1,1,0,P.c110);
  cg_fill(2,2,0,P.c220);
  cg_fill(3,3,0,P.c330);
  cg_fill(0,1,1,P.c011);
  cg_fill(1,0,1,P.c101);
  cg_fill(1,1,1,P.c111);
  cg_fill(1,2,1,P.c121);
  cg_fill(2,1,1,P.c211);
  cg_fill(2,2,1,P.c221);
  cg_fill(2,3,1,P.c231);
  cg_fill(3,2,1,P.c321);
  cg_fill(3,3,1,P.c331);
}

// ---------------- device helpers ----------------
__device__ __forceinline__ void afadd(float* p, float v){ unsafeAtomicAdd(p, v); }

__device__ __forceinline__ float soh(float r, float c){
  float d = (r - c) * 2.0f;
  float d2 = d*d;
  return (d2 < 1.0f) ? 1.14136f * expf(2.0f + 1.0f/(d2-1.0f)) : 0.0f;
}

__device__ __forceinline__ float4 lerp4(const float* __restrict__ w0,
                                        const float* __restrict__ w1,
                                        int j, float al){
  float4 p = *(const float4*)(w0+j);
  float4 q = *(const float4*)(w1+j);
  float4 r;
  r.x = fmaf(al, q.x-p.x, p.x);
  r.y = fmaf(al, q.y-p.y, p.y);
  r.z = fmaf(al, q.z-p.z, p.z);
  r.w = fmaf(al, q.w-p.w, p.w);
  return r;
}

// ---------------- radial MLP lookup table: tab[T_TAB][336] ----------------
// tab[t][0:272]  = relu(soh(r_t) @ W1) @ W2  / 16
// tab[t][272:336]= relu(soh(r_t) @ W1f) @ W2f / 16
__global__ __launch_bounds__(256) void k_table(
    const float* __restrict__ W1, const float* __restrict__ W2,
    const float* __restrict__ W1f, const float* __restrict__ W2f,
    float* __restrict__ tab)
{
  __shared__ float h[G_TAB][256];
  __shared__ float hf[G_TAB][256];
  const int c = threadIdx.x;
  const int t0 = blockIdx.x * G_TAB;
  const float dr = 2.5f / (float)(T_TAB-1);
  const float w1a = W1[c], w1b = W1[256+c], w1c = W1[512+c];
  const float f1a = W1f[c], f1b = W1f[256+c], f1c = W1f[512+c];
#pragma unroll
  for (int g=0; g<G_TAB; ++g){
    float r = (float)(t0+g) * dr;
    float e0 = soh(r,1.0f), e1 = soh(r,1.5f), e2 = soh(r,2.0f);
    h[g][c]  = fmaxf(e0*w1a + e1*w1b + e2*w1c, 0.0f);
    hf[g][c] = fmaxf(e0*f1a + e1*f1b + e2*f1c, 0.0f);
  }
  __syncthreads();
  for (int j = c; j < 336; j += 256){
    float acc[G_TAB];
#pragma unroll
    for (int g=0; g<G_TAB; ++g) acc[g]=0.0f;
    if (j < 272){
      for (int cc=0; cc<256; ++cc){
        float wv = W2[cc*272 + j];
#pragma unroll
        for (int g=0; g<G_TAB; ++g) acc[g] = fmaf(h[g][cc], wv, acc[g]);
      }
    } else {
      int jj = j - 272;
      for (int cc=0; cc<256; ++cc){
        float wv = W2f[cc*64 + jj];
#pragma unroll
        for (int g=0; g<G_TAB; ++g) acc[g] = fmaf(hf[g][cc], wv, acc[g]);
      }
    }
#pragma unroll
    for (int g=0; g<G_TAB; ++g) tab[(size_t)(t0+g)*336 + j] = acc[g] * 0.0625f;
  }
}

// ---------------- pass 1: SH per edge + scatter x = segsum(ea) ----------------
__global__ __launch_bounds__(256) void k_edge1(
    const float* __restrict__ pos, const int* __restrict__ src, const int* __restrict__ dst,
    int E, float* __restrict__ ea, float* __restrict__ rr, float* __restrict__ xacc)
{
  const int e = blockIdx.x*256 + threadIdx.x;
  if (e>=E) return;
  const int s = src[e], d = dst[e];
  float ax = pos[3*s+0]-pos[3*d+0];
  float ay = pos[3*s+1]-pos[3*d+1];
  float az = pos[3*s+2]-pos[3*d+2];
  float r = sqrtf(ax*ax+ay*ay+az*az);
  rr[e] = r;
  float ir = 1.0f/r;
  float x = ax*ir, y = ay*ir, z = az*ir;
  const float s3=1.73205081f, s5=2.23606798f, s15=3.87298335f;
  const float c33=2.09165007f, c32=10.2469508f, c31=1.62018517f, c30=1.32287566f, cp2=5.12347538f;
  float Y[16];
  Y[0]=1.0f;
  Y[1]=s3*y; Y[2]=s3*z; Y[3]=s3*x;
  Y[4]=s15*x*y; Y[5]=s15*y*z; Y[6]=0.5f*s5*(3.0f*z*z-1.0f); Y[7]=s15*x*z; Y[8]=0.5f*s15*(x*x-y*y);
  Y[9]=c33*y*(3.0f*x*x-y*y); Y[10]=c32*x*y*z; Y[11]=c31*y*(5.0f*z*z-1.0f);
  Y[12]=c30*(5.0f*z*z*z-3.0f*z); Y[13]=c31*x*(5.0f*z*z-1.0f); Y[14]=cp2*z*(x*x-y*y);
  Y[15]=c33*x*(x*x-3.0f*y*y);
  float4* o4 = (float4*)(ea + (size_t)e*16);
  o4[0]=make_float4(Y[0],Y[1],Y[2],Y[3]);
  o4[1]=make_float4(Y[4],Y[5],Y[6],Y[7]);
  o4[2]=make_float4(Y[8],Y[9],Y[10],Y[11]);
  o4[3]=make_float4(Y[12],Y[13],Y[14],Y[15]);
  float* xa = xacc + (size_t)d*16;
#pragma unroll
  for (int i=0;i<16;++i) afadd(xa+i, Y[i]);
}

// ---------------- pass 2: fctp1(x[src], ea, w) scattered into x2 ----------------
__global__ __launch_bounds__(256) void k_edge2(
    const int* __restrict__ src, const int* __restrict__ dst, int E,
    const float* __restrict__ ea, const float* __restrict__ rr,
    const float* __restrict__ xacc, const float* __restrict__ tab,
    float* __restrict__ x2, CGPack cg)
{
  const int e = blockIdx.x*256 + threadIdx.x;
  if (e>=E) return;
  const float r = rr[e];
  float f = r * 1638.0f;                       // (T_TAB-1)/2.5
  int i0 = (int)f; if (i0 > T_TAB-2) i0 = T_TAB-2;
  const float al = f - (float)i0;
  const float* __restrict__ w0 = tab + (size_t)i0*336;
  const float* __restrict__ w1 = w0 + 336;

  float Y[16], X[16];
  {
    const float4* p4 = (const float4*)(ea + (size_t)e*16);
    float4 a=p4[0],b=p4[1],c=p4[2],d4=p4[3];
    Y[0]=a.x;Y[1]=a.y;Y[2]=a.z;Y[3]=a.w; Y[4]=b.x;Y[5]=b.y;Y[6]=b.z;Y[7]=b.w;
    Y[8]=c.x;Y[9]=c.y;Y[10]=c.z;Y[11]=c.w; Y[12]=d4.x;Y[13]=d4.y;Y[14]=d4.z;Y[15]=d4.w;
  }
  {
    const int s = src[e];
    const float inv = 0.5129891760f;           // 1/sqrt(3.8)
    const float4* q4 = (const float4*)(xacc + (size_t)s*16);
    float4 a=q4[0],b=q4[1],c=q4[2],d4=q4[3];
    X[0]=a.x*inv;X[1]=a.y*inv;X[2]=a.z*inv;X[3]=a.w*inv;
    X[4]=b.x*inv;X[5]=b.y*inv;X[6]=b.z*inv;X[7]=b.w*inv;
    X[8]=c.x*inv;X[9]=c.y*inv;X[10]=c.z*inv;X[11]=c.w*inv;
    X[12]=d4.x*inv;X[13]=d4.y*inv;X[14]=d4.z*inv;X[15]=d4.w*inv;
  }

  // ---- CG contractions (dense, fully unrolled) ----
  float t0 = cg.c000[0]*X[0]*Y[0];
  float t1=0.0f, t2=0.0f, t3=0.0f;
#pragma unroll
  for (int i=0;i<3;++i)
#pragma unroll
    for (int j=0;j<3;++j) t1 = fmaf(X[1+i]*Y[1+j], cg.c110[i*3+j], t1);
#pragma unroll
  for (int i=0;i<5;++i)
#pragma unroll
    for (int j=0;j<5;++j) t2 = fmaf(X[4+i]*Y[4+j], cg.c220[i*5+j], t2);
#pragma unroll
  for (int i=0;i<7;++i)
#pragma unroll
    for (int j=0;j<7;++j) t3 = fmaf(X[9+i]*Y[9+j], cg.c330[i*7+j], t3);

  float v01[3]={0,0,0}, v10[3]={0,0,0}, v11[3]={0,0,0}, v12[3]={0,0,0},
        v21[3]={0,0,0}, v22[3]={0,0,0}, v23[3]={0,0,0}, v32[3]={0,0,0}, v33[3]={0,0,0};
#pragma unroll
  for (int j=0;j<3;++j){ float t=X[0]*Y[1+j];
#pragma unroll
    for (int k=0;k<3;++k) v01[k]=fmaf(t, cg.c011[j*3+k], v01[k]); }
#pragma unroll
  for (int i=0;i<3;++i){ float t=X[1+i]*Y[0];
#pragma unroll
    for (int k=0;k<3;++k) v10[k]=fmaf(t, cg.c101[i*3+k], v10[k]); }
#pragma unroll
  for (int i=0;i<3;++i)
#pragma unroll
    for (int j=0;j<3;++j){ float t=X[1+i]*Y[1+j];
#pragma unroll
      for (int k=0;k<3;++k) v11[k]=fmaf(t, cg.c111[(i*3+j)*3+k], v11[k]); }
#pragma unroll
  for (int i=0;i<3;++i)
#pragma unroll
    for (int j=0;j<5;++j){ float t=X[1+i]*Y[4+j];
#pragma unroll
      for (int k=0;k<3;++k) v12[k]=fmaf(t, cg.c121[(i*5+j)*3+k], v12[k]); }
#pragma unroll
  for (int i=0;i<5;++i)
#pragma unroll
    for (int j=0;j<3;++j){ float t=X[4+i]*Y[1+j];
#pragma unroll
      for (int k=0;k<3;++k) v21[k]=fmaf(t, cg.c211[(i*3+j)*3+k], v21[k]); }
#pragma unroll
  for (int i=0;i<5;++i)
#pragma unroll
    for (int j=0;j<5;++j){ float t=X[4+i]*Y[4+j];
#pragma unroll
      for (int k=0;k<3;++k) v22[k]=fmaf(t, cg.c221[(i*5+j)*3+k], v22[k]); }
#pragma unroll
  for (int i=0;i<5;++i)
#pragma unroll
    for (int j=0;j<7;++j){ float t=X[4+i]*Y[9+j];
#pragma unroll
      for (int k=0;k<3;++k) v23[k]=fmaf(t, cg.c231[(i*7+j)*3+k], v23[k]); }
#pragma unroll
  for (int i=0;i<7;++i)
#pragma unroll
    for (int j=0;j<5;++j){ float t=X[9+i]*Y[4+j];
#pragma unroll
      for (int k=0;k<3;++k) v32[k]=fmaf(t, cg.c321[(i*5+j)*3+k], v32[k]); }
#pragma unroll
  for (int i=0;i<7;++i)
#pragma unroll
    for (int j=0;j<7;++j){ float t=X[9+i]*Y[9+j];
#pragma unroll
      for (int k=0;k<3;++k) v33[k]=fmaf(t, cg.c331[(i*7+j)*3+k], v33[k]); }

  // ---- apply per-edge weights (interpolated) and scatter ----
  const int d = dst[e];
  float* __restrict__ o = x2 + (size_t)d*160;
  const float H=0.5f, I6=0.4082482905f, I3=0.5773502692f;

#pragma unroll
  for (int u=0; u<16; u+=4){                   // io0: scalars even (16), fan 4
    float4 A=lerp4(w0,w1,u,al), B=lerp4(w0,w1,64+u,al), C4=lerp4(w0,w1,144+u,al), D4=lerp4(w0,w1,224+u,al);
    float wa[4]={A.x,A.y,A.z,A.w}, wb[4]={B.x,B.y,B.z,B.w}, wc[4]={C4.x,C4.y,C4.z,C4.w}, wd[4]={D4.x,D4.y,D4.z,D4.w};
#pragma unroll
    for (int uu=0; uu<4; ++uu)
      afadd(o+u+uu, H*(wa[uu]*t0 + wb[uu]*t1 + wc[uu]*t2 + wd[uu]*t3));
  }
#pragma unroll
  for (int u=0; u<8; u+=4){                    // io2: scalars even (8), fan 4
    float4 A=lerp4(w0,w1,16+u,al), B=lerp4(w0,w1,80+u,al), C4=lerp4(w0,w1,160+u,al), D4=lerp4(w0,w1,240+u,al);
    float wa[4]={A.x,A.y,A.z,A.w}, wb[4]={B.x,B.y,B.z,B.w}, wc[4]={C4.x,C4.y,C4.z,C4.w}, wd[4]={D4.x,D4.y,D4.z,D4.w};
#pragma unroll
    for (int uu=0; uu<4; ++uu)
      afadd(o+32+u+uu, H*(wa[uu]*t0 + wb[uu]*t1 + wc[uu]*t2 + wd[uu]*t3));
  }
#pragma unroll
  for (int u=0; u<8; u+=4){                    // io4: scalars even (8), fan 4
    float4 A=lerp4(w0,w1,24+u,al), B=lerp4(w0,w1,88+u,al), C4=lerp4(w0,w1,168+u,al), D4=lerp4(w0,w1,248+u,al);
    float wa[4]={A.x,A.y,A.z,A.w}, wb[4]={B.x,B.y,B.z,B.w}, wc[4]={C4.x,C4.y,C4.z,C4.w}, wd[4]={D4.x,D4.y,D4.z,D4.w};
#pragma unroll
    for (int uu=0; uu<4; ++uu)
      afadd(o+48+u+uu, H*(wa[uu]*t0 + wb[uu]*t1 + wc[uu]*t2 + wd[uu]*t3));
  }
#pragma unroll
  for (int u=0; u<16; u+=4){                   // io6: l=1 odd (16x3), fan 6
    float4 A=lerp4(w0,w1,32+u,al), B=lerp4(w0,w1,48+u,al), C4=lerp4(w0,w1,112+u,al),
           D4=lerp4(w0,w1,128+u,al), E4=lerp4(w0,w1,192+u,al), F4=lerp4(w0,w1,208+u,al);
    float wa[4]={A.x,A.y,A.z,A.w}, wb[4]={B.x,B.y,B.z,B.w}, wc[4]={C4.x,C4.y,C4.z,C4.w},
          wd[4]={D4.x,D4.y,D4.z,D4.w}, we[4]={E4.x,E4.y,E4.z,E4.w}, wg[4]={F4.x,F4.y,F4.z,F4.w};
#pragma unroll
    for (int uu=0; uu<4; ++uu)
#pragma unroll
      for (int k=0;k<3;++k)
        afadd(o+64+(u+uu)*3+k,
              I6*(wa[uu]*v01[k]+wb[uu]*v10[k]+wc[uu]*v12[k]+wd[uu]*v21[k]+we[uu]*v23[k]+wg[uu]*v32[k]));
  }
#pragma unroll
  for (int u=0; u<16; u+=4){                   // io7: l=1 even (16x3), fan 3
    float4 A=lerp4(w0,w1,96+u,al), B=lerp4(w0,w1,176+u,al), C4=lerp4(w0,w1,256+u,al);
    float wa[4]={A.x,A.y,A.z,A.w}, wb[4]={B.x,B.y,B.z,B.w}, wc[4]={C4.x,C4.y,C4.z,C4.w};
#pragma unroll
    for (int uu=0; uu<4; ++uu)
#pragma unroll
      for (int k=0;k<3;++k)
        afadd(o+112+(u+uu)*3+k, I3*(wa[uu]*v11[k]+wb[uu]*v22[k]+wc[uu]*v33[k]));
  }
}

// ---------------- pass 3: gate ----------------
__global__ __launch_bounds__(256) void k_gate(
    const float* __restrict__ x2, float* __restrict__ xg, int N)
{
  const int n = blockIdx.x*256 + threadIdx.x;
  if (n>=N) return;
  const float* __restrict__ x = x2 + (size_t)n*160;
  float* __restrict__ g = xg + (size_t)n*128;
  const float inv = 0.5129891760f;
  float gg[16], gh[16];
#pragma unroll
  for (int u=0;u<8;++u){
    gg[u]   = fmaxf(x[32+u]*inv, 0.0f);
    gg[8+u] = tanhf(x[40+u]*inv);
    gh[u]   = fmaxf(x[48+u]*inv, 0.0f);
    gh[8+u] = tanhf(x[56+u]*inv);
  }
#pragma unroll
  for (int i=0;i<16;++i) g[i]    = fmaxf(x[i]*inv, 0.0f);
#pragma unroll
  for (int i=0;i<16;++i) g[16+i] = fabsf(x[16+i]*inv);
#pragma unroll
  for (int u=0;u<16;++u)
#pragma unroll
    for (int k=0;k<3;++k){
      g[32+u*3+k] = x[64+u*3+k]*inv*gg[u];
      g[80+u*3+k] = x[112+u*3+k]*inv*gh[u];
    }
}

// ---------------- pass 4: fctp2 + final scatter ----------------
__global__ __launch_bounds__(256) void k_edge3(
    const int* __restrict__ src, const int* __restrict__ dst, int E,
    const float* __restrict__ ea, const float* __restrict__ rr,
    const float* __restrict__ xg, const float* __restrict__ tab,
    float* __restrict__ out, CGPack cg)
{
  const int e = blockIdx.x*256 + threadIdx.x;
  if (e>=E) return;
  const float r = rr[e];
  float f = r * 1638.0f;
  int i0 = (int)f; if (i0 > T_TAB-2) i0 = T_TAB-2;
  const float al = f - (float)i0;
  const float* __restrict__ w0 = tab + (size_t)i0*336 + 272;
  const float* __restrict__ w1 = w0 + 336;
  float wf[64];
#pragma unroll
  for (int j=0;j<64;j+=4){
    float4 p = *(const float4*)(w0+j);
    float4 q = *(const float4*)(w1+j);
    wf[j+0]=fmaf(al,q.x-p.x,p.x);
    wf[j+1]=fmaf(al,q.y-p.y,p.y);
    wf[j+2]=fmaf(al,q.z-p.z,p.z);
    wf[j+3]=fmaf(al,q.w-p.w,p.w);
  }
  float Y[16];
  {
    const float4* p4 = (const float4*)(ea + (size_t)e*16);
    float4 a=p4[0],b=p4[1],c=p4[2],d4=p4[3];
    Y[0]=a.x;Y[1]=a.y;Y[2]=a.z;Y[3]=a.w; Y[4]=b.x;Y[5]=b.y;Y[6]=b.z;Y[7]=b.w;
    Y[8]=c.x;Y[9]=c.y;Y[10]=c.z;Y[11]=c.w; Y[12]=d4.x;Y[13]=d4.y;Y[14]=d4.z;Y[15]=d4.w;
  }
  const float* __restrict__ g = xg + (size_t)src[e]*128;
  float se[16], vo[48], ve[48];
#pragma unroll
  for (int jj=0;jj<4;++jj){ float4 t=((const float4*)g)[jj];
    se[4*jj]=t.x; se[4*jj+1]=t.y; se[4*jj+2]=t.z; se[4*jj+3]=t.w; }
#pragma unroll
  for (int jj=0;jj<12;++jj){ float4 t=((const float4*)(g+32))[jj];
    vo[4*jj]=t.x; vo[4*jj+1]=t.y; vo[4*jj+2]=t.z; vo[4*jj+3]=t.w; }
#pragma unroll
  for (int jj=0;jj<12;++jj){ float4 t=((const float4*)(g+80))[jj];
    ve[4*jj]=t.x; ve[4*jj+1]=t.y; ve[4*jj+2]=t.z; ve[4*jj+3]=t.w; }

  float SA=0.0f;
#pragma unroll
  for (int u=0;u<16;++u) SA = fmaf(wf[u], se[u], SA);
  float AB[3]={0,0,0}, AC[3]={0,0,0}, AD[3]={0,0,0};
#pragma unroll
  for (int u=0;u<16;++u)
#pragma unroll
    for (int i=0;i<3;++i){
      AB[i]=fmaf(wf[16+u], vo[u*3+i], AB[i]);
      AC[i]=fmaf(wf[32+u], vo[u*3+i], AC[i]);
      AD[i]=fmaf(wf[48+u], ve[u*3+i], AD[i]);
    }
  float e2[3]={0,0,0};
#pragma unroll
  for (int j=0;j<3;++j){ float t=SA*Y[1+j];
#pragma unroll
    for (int k=0;k<3;++k) e2[k]=fmaf(t, cg.c011[j*3+k], e2[k]); }
#pragma unroll
  for (int i=0;i<3;++i){ float t=AB[i]*Y[0];
#pragma unroll
    for (int k=0;k<3;++k) e2[k]=fmaf(t, cg.c101[i*3+k], e2[k]); }
#pragma unroll
  for (int i=0;i<3;++i)
#pragma unroll
    for (int j=0;j<5;++j){ float t=AC[i]*Y[4+j];
#pragma unroll
      for (int k=0;k<3;++k) e2[k]=fmaf(t, cg.c121[(i*5+j)*3+k], e2[k]); }
#pragma unroll
  for (int i=0;i<3;++i)
#pragma unroll
    for (int j=0;j<3;++j){ float t=AD[i]*Y[1+j];
#pragma unroll
      for (int k=0;k<3;++k) e2[k]=fmaf(t, cg.c111[(i*3+j)*3+k], e2[k]); }

  const float sc = 0.0641236437f;  // (1/sqrt(64)) * 1/sqrt(3.8)
  const int d = dst[e];
  afadd(out + (size_t)d*3 + 0, e2[0]*sc);
  afadd(out + (size_t)d*3 + 1, e2[1]*sc);
  afadd(out + (size_t)d*3 + 2, e2[2]*sc);
}

// ---------------- host launcher ----------------
extern "C" void kernel_launch(void* const* d_in, const int* in_sizes, int n_in,
                              void* d_out, int out_size, void* d_ws, size_t ws_size,
                              hipStream_t stream)
{
  (void)n_in; (void)ws_size;
  const float* pos = (const float*)d_in[0];
  const int*   src = (const int*)d_in[1];
  const int*   dst = (const int*)d_in[2];
  const float* W1  = (const float*)d_in[3];
  const float* W2  = (const float*)d_in[4];
  const float* W1f = (const float*)d_in[5];
  const float* W2f = (const float*)d_in[6];
  const int E = in_sizes[1];

  char* ws = (char*)d_ws;
  float* ea   = (float*)ws;                    // E*16
  float* rr   = ea + (size_t)E*16;             // E
  float* xacc = rr + (size_t)E;                // NN*16
  float* x2   = xacc + (size_t)NN*16;          // NN*160
  float* xg   = x2 + (size_t)NN*160;           // NN*128
  float* tab  = xg + (size_t)NN*128;           // T_TAB*336

  CGPack cg;
  build_cg(cg);

  hipMemsetAsync(xacc, 0, (size_t)NN*16*sizeof(float), stream);
  hipMemsetAsync(x2,   0, (size_t)NN*160*sizeof(float), stream);
  hipMemsetAsync(d_out,0, (size_t)out_size*sizeof(float), stream);

  k_table<<<T_TAB/G_TAB, 256, 0, stream>>>(W1, W2, W1f, W2f, tab);
  const int nb = (E + 255) / 256;
  k_edge1<<<nb, 256, 0, stream>>>(pos, src, dst, E, ea, rr, xacc);
  k_edge2<<<nb, 256, 0, stream>>>(src, dst, E, ea, rr, xacc, tab, x2, cg);
  k_gate<<<(NN + 255) / 256, 256, 0, stream>>>(x2, xg, NN);
  k_edge3<<<nb, 256, 0, stream>>>(src, dst, E, ea, rr, xg, tab, (float*)d_out, cg);
}

// Round 2
// 422.550 us; speedup vs baseline: 4.6841x; 4.6841x over previous
//
#include <hip/hip_runtime.h>
#include <cmath>
#include <complex>

#define T_TAB 4096
#define G_TAB 8
#define NN 16384
#define CH 32

// ---------------- CG tables (exact host-side port of the reference) ----------------
struct CGPack {
  float c000[1];
  float c110[9];
  float c220[25];
  float c330[49];
  float c011[9];
  float c101[9];
  float c111[27];
  float c121[45];
  float c211[45];
  float c221[75];
  float c231[105];
  float c321[105];
  float c331[147];
};

static double factd(int n){ double r=1.0; for(int i=2;i<=n;++i) r*=(double)i; return r; }

static double cg_coef(int j1,int m1,int j2,int m2,int j3,int m3){
  double pref = sqrt((2.0*j3+1.0)*factd(j3+j1-j2)*factd(j3-j1+j2)*factd(j1+j2-j3)/factd(j1+j2+j3+1));
  pref *= sqrt(factd(j3+m3)*factd(j3-m3)*factd(j1-m1)*factd(j1+m1)*factd(j2-m2)*factd(j2+m2));
  double s=0.0;
  for(int k=0;k<=j1+j2-j3;++k){
    int a0=k,a1=j1+j2-j3-k,a2=j1-m1-k,a3=j2+m2-k,a4=j3-j2+m1+k,a5=j3-j1-m2+k;
    if(a0<0||a1<0||a2<0||a3<0||a4<0||a5<0) continue;
    double d=factd(a0)*factd(a1)*factd(a2)*factd(a3)*factd(a4)*factd(a5);
    s += ((k&1)?-1.0:1.0)/d;
  }
  return pref*s;
}

static void u_fill(int l, std::complex<double> U[7][7]){
  for(int i=0;i<7;++i) for(int j=0;j<7;++j) U[i][j]=std::complex<double>(0.0,0.0);
  const double is2 = 1.0/sqrt(2.0);
  U[l][l]=1.0;
  for(int m=1;m<=l;++m){
    double sgn = (m&1)?-1.0:1.0;
    U[l+m][l+m] = sgn*is2;
    U[l+m][l-m] = is2;
    U[l-m][l-m] = std::complex<double>(0.0, is2);
    U[l-m][l+m] = std::complex<double>(0.0, -sgn*is2);
  }
}

static void cg_fill(int l1,int l2,int l3, float* out){
  int n1=2*l1+1,n2=2*l2+1,n3=2*l3+1;
  double Cc[7][7][7];
  for(int a=0;a<7;++a)for(int b=0;b<7;++b)for(int c=0;c<7;++c) Cc[a][b][c]=0.0;
  for(int m1=-l1;m1<=l1;++m1)
    for(int m2=-l2;m2<=l2;++m2){
      int m3=m1+m2;
      if(m3>=-l3&&m3<=l3) Cc[m1+l1][m2+l2][m3+l3]=cg_coef(l1,m1,l2,m2,l3,m3);
    }
  std::complex<double> U1[7][7],U2[7][7],U3[7][7];
  u_fill(l1,U1); u_fill(l2,U2); u_fill(l3,U3);
  std::complex<double> Cr[343];
  double sre=0.0,sim=0.0;
  for(int a=0;a<n1;++a)for(int b=0;b<n2;++b)for(int c=0;c<n3;++c){
    std::complex<double> acc(0.0,0.0);
    for(int u=0;u<n1;++u)for(int v=0;v<n2;++v)for(int w=0;w<n3;++w){
      double cc=Cc[u][v][w];
      if(cc==0.0) continue;
      acc += U1[a][u]*U2[b][v]*std::conj(U3[c][w])*cc;
    }
    Cr[(a*n2+b)*n3+c]=acc;
    sre+=fabs(acc.real()); sim+=fabs(acc.imag());
  }
  bool useim = sim>sre;
  for(int idx=0;idx<n1*n2*n3;++idx) out[idx]=(float)(useim?Cr[idx].imag():Cr[idx].real());
}

static void build_cg(CGPack& P){
  cg_fill(0,0,0,P.c000);
  cg_fill(1,1,0,P.c110);
  cg_fill(2,2,0,P.c220);
  cg_fill(3,3,0,P.c330);
  cg_fill(0,1,1,P.c011);
  cg_fill(1,0,1,P.c101);
  cg_fill(1,1,1,P.c111);
  cg_fill(1,2,1,P.c121);
  cg_fill(2,1,1,P.c211);
  cg_fill(2,2,1,P.c221);
  cg_fill(2,3,1,P.c231);
  cg_fill(3,2,1,P.c321);
  cg_fill(3,3,1,P.c331);
}

// ---------------- device helpers ----------------
__device__ __forceinline__ float soh(float r, float c){
  float d = (r - c) * 2.0f;
  float d2 = d*d;
  return (d2 < 1.0f) ? 1.14136f * expf(2.0f + 1.0f/(d2-1.0f)) : 0.0f;
}

// ---------------- radial MLP lookup table: tab[T_TAB][336] ----------------
__global__ __launch_bounds__(256) void k_table(
    const float* __restrict__ W1, const float* __restrict__ W2,
    const float* __restrict__ W1f, const float* __restrict__ W2f,
    float* __restrict__ tab)
{
  __shared__ float h[G_TAB][256];
  __shared__ float hf[G_TAB][256];
  const int c = threadIdx.x;
  const int t0 = blockIdx.x * G_TAB;
  const float dr = 2.5f / (float)(T_TAB-1);
  const float w1a = W1[c], w1b = W1[256+c], w1c = W1[512+c];
  const float f1a = W1f[c], f1b = W1f[256+c], f1c = W1f[512+c];
#pragma unroll
  for (int g=0; g<G_TAB; ++g){
    float r = (float)(t0+g) * dr;
    float e0 = soh(r,1.0f), e1 = soh(r,1.5f), e2 = soh(r,2.0f);
    h[g][c]  = fmaxf(e0*w1a + e1*w1b + e2*w1c, 0.0f);
    hf[g][c] = fmaxf(e0*f1a + e1*f1b + e2*f1c, 0.0f);
  }
  __syncthreads();
  for (int j = c; j < 336; j += 256){
    float acc[G_TAB];
#pragma unroll
    for (int g=0; g<G_TAB; ++g) acc[g]=0.0f;
    if (j < 272){
      for (int cc=0; cc<256; ++cc){
        float wv = W2[cc*272 + j];
#pragma unroll
        for (int g=0; g<G_TAB; ++g) acc[g] = fmaf(h[g][cc], wv, acc[g]);
      }
    } else {
      int jj = j - 272;
      for (int cc=0; cc<256; ++cc){
        float wv = W2f[cc*64 + jj];
#pragma unroll
        for (int g=0; g<G_TAB; ++g) acc[g] = fmaf(hf[g][cc], wv, acc[g]);
      }
    }
#pragma unroll
    for (int g=0; g<G_TAB; ++g) tab[(size_t)(t0+g)*336 + j] = acc[g] * 0.0625f;
  }
}

// ---------------- rowptr: dst is globally non-decreasing -> CSR via binary search ----
__global__ __launch_bounds__(256) void k_rowptr(
    const int* __restrict__ dst, int E, int* __restrict__ rowptr)
{
  const int n = blockIdx.x*256 + threadIdx.x;
  if (n > NN) return;
  int lo=0, hi=E;
  while (lo < hi){ int mid=(lo+hi)>>1; if (dst[mid] < n) lo=mid+1; else hi=mid; }
  rowptr[n]=lo;
}

// ---------------- x = segsum(sph_harm) gather: 4 threads per node ----------------
__global__ __launch_bounds__(256) void k_x(
    const float* __restrict__ pos, const int* __restrict__ src,
    const int* __restrict__ rowptr, float* __restrict__ xacc)
{
  const int t = blockIdx.x*256 + threadIdx.x;
  const int n = t>>2, q = t&3;
  if (n>=NN) return;
  const int r0=rowptr[n], r1=rowptr[n+1];
  const float pdx=pos[3*n], pdy=pos[3*n+1], pdz=pos[3*n+2];
  const float s3=1.73205081f, s5=2.23606798f, s15=3.87298335f;
  const float c33=2.09165007f, c32=10.2469508f, c31=1.62018517f, c30=1.32287566f, cp2=5.12347538f;
  float a0=0.f,a1=0.f,a2=0.f,a3=0.f;
  for (int e=r0;e<r1;++e){
    const int s=src[e];
    float ax=pos[3*s]-pdx, ay=pos[3*s+1]-pdy, az=pos[3*s+2]-pdz;
    float ir = 1.0f/sqrtf(ax*ax+ay*ay+az*az);
    float x=ax*ir, y=ay*ir, z=az*ir;
    if (q==0){ a0+=1.0f; a1+=s3*y; a2+=s3*z; a3+=s3*x; }
    else if (q==1){ a0+=s15*x*y; a1+=s15*y*z; a2+=0.5f*s5*(3.0f*z*z-1.0f); a3+=s15*x*z; }
    else if (q==2){ a0+=0.5f*s15*(x*x-y*y); a1+=c33*y*(3.0f*x*x-y*y); a2+=c32*x*y*z; a3+=c31*y*(5.0f*z*z-1.0f); }
    else { a0+=c30*(5.0f*z*z*z-3.0f*z); a1+=c31*x*(5.0f*z*z-1.0f); a2+=cp2*z*(x*x-y*y); a3+=c33*x*(x*x-3.0f*y*y); }
  }
  *(float4*)(xacc + (size_t)n*16 + q*4) = make_float4(a0,a1,a2,a3);
}

// ---------------- fctp1 gather: 2 nodes/block, 128 threads/node = 1 per output ----
// Phase 1: <=CH edges -> 31 CG intermediates (+i0,al) in LDS.
// Phase 2: each output thread does 6 weight-lerp FMAs per edge, plain store.
__global__ __launch_bounds__(256) void k_tp1(
    const float* __restrict__ pos, const int* __restrict__ src,
    const int* __restrict__ rowptr, const float* __restrict__ xacc,
    const float* __restrict__ tab, float* __restrict__ x2, CGPack cg)
{
  const int half = threadIdx.x >> 7;
  const int c    = threadIdx.x & 127;
  const int node = blockIdx.x*2 + half;
  __shared__ float SI[2][CH][34];
  __shared__ int   SiT[2][CH];
  __shared__ int   sdeg[2];
  const int r0 = rowptr[node], r1 = rowptr[node+1];
  if (c==0) sdeg[half] = r1 - r0;
  __syncthreads();
  const int maxdeg = max(sdeg[0], sdeg[1]);
  const int nch = (maxdeg + CH - 1) / CH;

  // per-thread output mapping
  int wo[6], io[6], outOff; float scale;
  if (c < 32){
    wo[0]=c; wo[1]=64+c; wo[2]=144+c; wo[3]=224+c; wo[4]=0; wo[5]=0;
    io[0]=0; io[1]=1; io[2]=2; io[3]=3; io[4]=31; io[5]=31;
    outOff = c + (c<16 ? 0 : (c<24 ? 16 : 24));
    scale = 0.5f;
  } else if (c < 80){
    int idx=c-32, u=idx/3, k=idx-3*u;
    wo[0]=32+u; wo[1]=48+u; wo[2]=112+u; wo[3]=128+u; wo[4]=192+u; wo[5]=208+u;
    io[0]=4+k; io[1]=7+k; io[2]=10+k; io[3]=13+k; io[4]=16+k; io[5]=19+k;
    outOff = 64+idx; scale = 0.4082482905f;
  } else {
    int idx=c-80, u=idx/3, k=idx-3*u;
    wo[0]=96+u; wo[1]=176+u; wo[2]=256+u; wo[3]=0; wo[4]=0; wo[5]=0;
    io[0]=22+k; io[1]=25+k; io[2]=28+k; io[3]=31; io[4]=31; io[5]=31;
    outOff = 112+idx; scale = 0.5773502692f;
  }

  const float pdx=pos[3*node], pdy=pos[3*node+1], pdz=pos[3*node+2];
  float acc = 0.f;

  for (int t=0; t<nch; ++t){
    const int e0 = r0 + t*CH;
    const int cnt = min(CH, r1-e0);   // may be <= 0
    __syncthreads();
    if (c < cnt){
      const int e = e0 + c;
      const int s = src[e];
      float ax=pos[3*s]-pdx, ay=pos[3*s+1]-pdy, az=pos[3*s+2]-pdz;
      float r = sqrtf(ax*ax+ay*ay+az*az);
      float ir = 1.0f/r;
      float x=ax*ir, y=ay*ir, z=az*ir;
      float f = r * 1638.0f;
      int i0 = (int)f; if (i0 > T_TAB-2) i0 = T_TAB-2;
      float al = f - (float)i0;

      const float s3=1.73205081f, s5=2.23606798f, s15=3.87298335f;
      const float c33=2.09165007f, c32=10.2469508f, c31=1.62018517f, c30=1.32287566f, cp2=5.12347538f;
      float Y[16];
      Y[0]=1.0f;
      Y[1]=s3*y; Y[2]=s3*z; Y[3]=s3*x;
      Y[4]=s15*x*y; Y[5]=s15*y*z; Y[6]=0.5f*s5*(3.0f*z*z-1.0f); Y[7]=s15*x*z; Y[8]=0.5f*s15*(x*x-y*y);
      Y[9]=c33*y*(3.0f*x*x-y*y); Y[10]=c32*x*y*z; Y[11]=c31*y*(5.0f*z*z-1.0f);
      Y[12]=c30*(5.0f*z*z*z-3.0f*z); Y[13]=c31*x*(5.0f*z*z-1.0f); Y[14]=cp2*z*(x*x-y*y);
      Y[15]=c33*x*(x*x-3.0f*y*y);
      float X[16];
      {
        const float inv = 0.5129891760f;           // 1/sqrt(3.8)
        const float4* q4 = (const float4*)(xacc + (size_t)s*16);
        float4 a=q4[0],b=q4[1],cc4=q4[2],d4=q4[3];
        X[0]=a.x*inv;X[1]=a.y*inv;X[2]=a.z*inv;X[3]=a.w*inv;
        X[4]=b.x*inv;X[5]=b.y*inv;X[6]=b.z*inv;X[7]=b.w*inv;
        X[8]=cc4.x*inv;X[9]=cc4.y*inv;X[10]=cc4.z*inv;X[11]=cc4.w*inv;
        X[12]=d4.x*inv;X[13]=d4.y*inv;X[14]=d4.z*inv;X[15]=d4.w*inv;
      }
      float t0v = cg.c000[0]*X[0]*Y[0];
      float t1v=0.f, t2v=0.f, t3v=0.f;
#pragma unroll
      for (int i=0;i<3;++i)
#pragma unroll
        for (int j=0;j<3;++j) t1v = fmaf(X[1+i]*Y[1+j], cg.c110[i*3+j], t1v);
#pragma unroll
      for (int i=0;i<5;++i)
#pragma unroll
        for (int j=0;j<5;++j) t2v = fmaf(X[4+i]*Y[4+j], cg.c220[i*5+j], t2v);
#pragma unroll
      for (int i=0;i<7;++i)
#pragma unroll
        for (int j=0;j<7;++j) t3v = fmaf(X[9+i]*Y[9+j], cg.c330[i*7+j], t3v);

      float v01[3]={0,0,0}, v10[3]={0,0,0}, v11[3]={0,0,0}, v12[3]={0,0,0},
            v21[3]={0,0,0}, v22[3]={0,0,0}, v23[3]={0,0,0}, v32[3]={0,0,0}, v33[3]={0,0,0};
#pragma unroll
      for (int j=0;j<3;++j){ float tt=X[0]*Y[1+j];
#pragma unroll
        for (int k=0;k<3;++k) v01[k]=fmaf(tt, cg.c011[j*3+k], v01[k]); }
#pragma unroll
      for (int i=0;i<3;++i){ float tt=X[1+i]*Y[0];
#pragma unroll
        for (int k=0;k<3;++k) v10[k]=fmaf(tt, cg.c101[i*3+k], v10[k]); }
#pragma unroll
      for (int i=0;i<3;++i)
#pragma unroll
        for (int j=0;j<3;++j){ float tt=X[1+i]*Y[1+j];
#pragma unroll
          for (int k=0;k<3;++k) v11[k]=fmaf(tt, cg.c111[(i*3+j)*3+k], v11[k]); }
#pragma unroll
      for (int i=0;i<3;++i)
#pragma unroll
        for (int j=0;j<5;++j){ float tt=X[1+i]*Y[4+j];
#pragma unroll
          for (int k=0;k<3;++k) v12[k]=fmaf(tt, cg.c121[(i*5+j)*3+k], v12[k]); }
#pragma unroll
      for (int i=0;i<5;++i)
#pragma unroll
        for (int j=0;j<3;++j){ float tt=X[4+i]*Y[1+j];
#pragma unroll
          for (int k=0;k<3;++k) v21[k]=fmaf(tt, cg.c211[(i*3+j)*3+k], v21[k]); }
#pragma unroll
      for (int i=0;i<5;++i)
#pragma unroll
        for (int j=0;j<5;++j){ float tt=X[4+i]*Y[4+j];
#pragma unroll
          for (int k=0;k<3;++k) v22[k]=fmaf(tt, cg.c221[(i*5+j)*3+k], v22[k]); }
#pragma unroll
      for (int i=0;i<5;++i)
#pragma unroll
        for (int j=0;j<7;++j){ float tt=X[4+i]*Y[9+j];
#pragma unroll
          for (int k=0;k<3;++k) v23[k]=fmaf(tt, cg.c231[(i*7+j)*3+k], v23[k]); }
#pragma unroll
      for (int i=0;i<7;++i)
#pragma unroll
        for (int j=0;j<5;++j){ float tt=X[9+i]*Y[4+j];
#pragma unroll
          for (int k=0;k<3;++k) v32[k]=fmaf(tt, cg.c321[(i*5+j)*3+k], v32[k]); }
#pragma unroll
      for (int i=0;i<7;++i)
#pragma unroll
        for (int j=0;j<7;++j){ float tt=X[9+i]*Y[9+j];
#pragma unroll
          for (int k=0;k<3;++k) v33[k]=fmaf(tt, cg.c331[(i*7+j)*3+k], v33[k]); }

      float* SS = SI[half][c];
      SS[0]=t0v; SS[1]=t1v; SS[2]=t2v; SS[3]=t3v;
#pragma unroll
      for (int k=0;k<3;++k){
        SS[4+k]=v01[k]; SS[7+k]=v10[k]; SS[10+k]=v12[k]; SS[13+k]=v21[k];
        SS[16+k]=v23[k]; SS[19+k]=v32[k]; SS[22+k]=v11[k]; SS[25+k]=v22[k]; SS[28+k]=v33[k];
      }
      SS[31]=0.0f; SS[32]=al;
      SiT[half][c]=i0;
    }
    __syncthreads();
    for (int j=0;j<cnt;++j){
      const float* I = SI[half][j];
      const float al = I[32];
      const float* w0 = tab + (size_t)SiT[half][j]*336;
      const float* w1 = w0 + 336;
#pragma unroll
      for (int p=0;p<6;++p){
        float wa = w0[wo[p]], wb = w1[wo[p]];
        acc = fmaf(fmaf(al, wb-wa, wa), I[io[p]], acc);
      }
    }
  }
  x2[(size_t)node*160 + outOff] = scale*acc;
}

// ---------------- gate ----------------
__global__ __launch_bounds__(256) void k_gate(
    const float* __restrict__ x2, float* __restrict__ xg, int N)
{
  const int n = blockIdx.x*256 + threadIdx.x;
  if (n>=N) return;
  const float* __restrict__ x = x2 + (size_t)n*160;
  float* __restrict__ g = xg + (size_t)n*128;
  const float inv = 0.5129891760f;
  float gg[16], gh[16];
#pragma unroll
  for (int u=0;u<8;++u){
    gg[u]   = fmaxf(x[32+u]*inv, 0.0f);
    gg[8+u] = tanhf(x[40+u]*inv);
    gh[u]   = fmaxf(x[48+u]*inv, 0.0f);
    gh[8+u] = tanhf(x[56+u]*inv);
  }
#pragma unroll
  for (int i=0;i<16;++i) g[i]    = fmaxf(x[i]*inv, 0.0f);
#pragma unroll
  for (int i=0;i<16;++i) g[16+i] = fabsf(x[16+i]*inv);
#pragma unroll
  for (int u=0;u<16;++u)
#pragma unroll
    for (int k=0;k<3;++k){
      g[32+u*3+k] = x[64+u*3+k]*inv*gg[u];
      g[80+u*3+k] = x[112+u*3+k]*inv*gh[u];
    }
}

// ---------------- fctp2 per edge -> e2buf[E][4] ----------------
__global__ __launch_bounds__(256) void k_tp2(
    const float* __restrict__ pos, const int* __restrict__ src, const int* __restrict__ dst, int E,
    const float* __restrict__ xg, const float* __restrict__ tab,
    float* __restrict__ e2buf, CGPack cg)
{
  const int e = blockIdx.x*256 + threadIdx.x;
  if (e>=E) return;
  const int s = src[e], d = dst[e];
  float ax=pos[3*s]-pos[3*d], ay=pos[3*s+1]-pos[3*d+1], az=pos[3*s+2]-pos[3*d+2];
  float r = sqrtf(ax*ax+ay*ay+az*az);
  float ir = 1.0f/r;
  float x=ax*ir, y=ay*ir, z=az*ir;
  float f = r * 1638.0f;
  int i0 = (int)f; if (i0 > T_TAB-2) i0 = T_TAB-2;
  const float al = f - (float)i0;
  const float* __restrict__ w0 = tab + (size_t)i0*336 + 272;
  const float* __restrict__ w1 = w0 + 336;
  float wf[64];
#pragma unroll
  for (int j=0;j<64;j+=4){
    float4 p = *(const float4*)(w0+j);
    float4 q = *(const float4*)(w1+j);
    wf[j+0]=fmaf(al,q.x-p.x,p.x);
    wf[j+1]=fmaf(al,q.y-p.y,p.y);
    wf[j+2]=fmaf(al,q.z-p.z,p.z);
    wf[j+3]=fmaf(al,q.w-p.w,p.w);
  }
  const float s3=1.73205081f, s5=2.23606798f, s15=3.87298335f;
  float Y[16];
  Y[0]=1.0f;
  Y[1]=s3*y; Y[2]=s3*z; Y[3]=s3*x;
  Y[4]=s15*x*y; Y[5]=s15*y*z; Y[6]=0.5f*s5*(3.0f*z*z-1.0f); Y[7]=s15*x*z; Y[8]=0.5f*s15*(x*x-y*y);
  // l=3 SH unused in fctp2 outputs (paths only reach Y[0..8])
  const float* __restrict__ g = xg + (size_t)s*128;
  float se[16], vo[48], ve[48];
#pragma unroll
  for (int jj=0;jj<4;++jj){ float4 t=((const float4*)g)[jj];
    se[4*jj]=t.x; se[4*jj+1]=t.y; se[4*jj+2]=t.z; se[4*jj+3]=t.w; }
#pragma unroll
  for (int jj=0;jj<12;++jj){ float4 t=((const float4*)(g+32))[jj];
    vo[4*jj]=t.x; vo[4*jj+1]=t.y; vo[4*jj+2]=t.z; vo[4*jj+3]=t.w; }
#pragma unroll
  for (int jj=0;jj<12;++jj){ float4 t=((const float4*)(g+80))[jj];
    ve[4*jj]=t.x; ve[4*jj+1]=t.y; ve[4*jj+2]=t.z; ve[4*jj+3]=t.w; }

  float SA=0.0f;
#pragma unroll
  for (int u=0;u<16;++u) SA = fmaf(wf[u], se[u], SA);
  float AB[3]={0,0,0}, AC[3]={0,0,0}, AD[3]={0,0,0};
#pragma unroll
  for (int u=0;u<16;++u)
#pragma unroll
    for (int i=0;i<3;++i){
      AB[i]=fmaf(wf[16+u], vo[u*3+i], AB[i]);
      AC[i]=fmaf(wf[32+u], vo[u*3+i], AC[i]);
      AD[i]=fmaf(wf[48+u], ve[u*3+i], AD[i]);
    }
  float e2[3]={0,0,0};
#pragma unroll
  for (int j=0;j<3;++j){ float t=SA*Y[1+j];
#pragma unroll
    for (int k=0;k<3;++k) e2[k]=fmaf(t, cg.c011[j*3+k], e2[k]); }
#pragma unroll
  for (int i=0;i<3;++i){ float t=AB[i]*Y[0];
#pragma unroll
    for (int k=0;k<3;++k) e2[k]=fmaf(t, cg.c101[i*3+k], e2[k]); }
#pragma unroll
  for (int i=0;i<3;++i)
#pragma unroll
    for (int j=0;j<5;++j){ float t=AC[i]*Y[4+j];
#pragma unroll
      for (int k=0;k<3;++k) e2[k]=fmaf(t, cg.c121[(i*5+j)*3+k], e2[k]); }
#pragma unroll
  for (int i=0;i<3;++i)
#pragma unroll
    for (int j=0;j<3;++j){ float t=AD[i]*Y[1+j];
#pragma unroll
      for (int k=0;k<3;++k) e2[k]=fmaf(t, cg.c111[(i*3+j)*3+k], e2[k]); }

  *(float4*)(e2buf + (size_t)e*4) = make_float4(e2[0], e2[1], e2[2], 0.0f);
}

// ---------------- final gather: out[n] = sc * sum(e2buf over incoming edges) -------
__global__ __launch_bounds__(256) void k_out(
    const float* __restrict__ e2buf, const int* __restrict__ rowptr,
    float* __restrict__ out)
{
  const int t = blockIdx.x*256 + threadIdx.x;
  const int n = t>>2, k = t&3;
  if (n>=NN) return;
  const int r0=rowptr[n], r1=rowptr[n+1];
  float a=0.f;
  for (int e=r0;e<r1;++e) a += e2buf[(size_t)e*4 + k];
  const float sc = 0.0641236437f;  // (1/sqrt(64)) * 1/sqrt(3.8)
  if (k<3) out[(size_t)n*3 + k] = a*sc;
}

// ---------------- host launcher ----------------
extern "C" void kernel_launch(void* const* d_in, const int* in_sizes, int n_in,
                              void* d_out, int out_size, void* d_ws, size_t ws_size,
                              hipStream_t stream)
{
  (void)n_in; (void)ws_size; (void)out_size;
  const float* pos = (const float*)d_in[0];
  const int*   src = (const int*)d_in[1];
  const int*   dst = (const int*)d_in[2];
  const float* W1  = (const float*)d_in[3];
  const float* W2  = (const float*)d_in[4];
  const float* W1f = (const float*)d_in[5];
  const float* W2f = (const float*)d_in[6];
  const int E = in_sizes[1];

  char* ws = (char*)d_ws;
  float* xacc  = (float*)ws;                     // NN*16
  float* x2    = xacc + (size_t)NN*16;           // NN*160
  float* xg    = x2 + (size_t)NN*160;            // NN*128
  float* tab   = xg + (size_t)NN*128;            // T_TAB*336
  float* e2buf = tab + (size_t)T_TAB*336;        // E*4
  int*   rowptr= (int*)(e2buf + (size_t)E*4);    // NN+1

  CGPack cg;
  build_cg(cg);

  hipMemsetAsync(x2, 0, (size_t)NN*160*sizeof(float), stream);

  k_table<<<T_TAB/G_TAB, 256, 0, stream>>>(W1, W2, W1f, W2f, tab);
  k_rowptr<<<(NN+1+255)/256, 256, 0, stream>>>(dst, E, rowptr);
  k_x<<<(NN*4)/256, 256, 0, stream>>>(pos, src, rowptr, xacc);
  k_tp1<<<NN/2, 256, 0, stream>>>(pos, src, rowptr, xacc, tab, x2, cg);
  k_gate<<<(NN + 255) / 256, 256, 0, stream>>>(x2, xg, NN);
  k_tp2<<<(E + 255) / 256, 256, 0, stream>>>(pos, src, dst, E, xg, tab, e2buf, cg);
  k_out<<<(NN*4)/256, 256, 0, stream>>>(e2buf, rowptr, (float*)d_out);
}